// Round 1
// baseline (4843.032 us; speedup 1.0000x reference)
//
#include <hip/hip_runtime.h>
#include <cstdint>

#define F 64          // feature dim (in/hid/out all 64)
#define F4 (F/4)      // float4 chunks per row

// ---------------------------------------------------------------------------
// Scatter-sum aggregation: agg[dst] += h[src] over all edges.
// 16 threads per edge, each handles one float4 chunk (4 hw fp32 atomics).
// ---------------------------------------------------------------------------
__device__ inline void atomic_add_f32(float* p, float v) {
    unsafeAtomicAdd(p, v);   // hw global_atomic_add_f32 (CAS loop otherwise)
}

__global__ __launch_bounds__(256) void scatter_kernel(
    const float* __restrict__ h, const int* __restrict__ src,
    const int* __restrict__ dst, float* __restrict__ agg, int E) {
    int gid = blockIdx.x * 256 + threadIdx.x;
    int e = gid >> 4;
    if (e >= E) return;
    int c = gid & 15;
    int s = src[e];
    int d = dst[e];
    float4 v = ((const float4*)h)[(size_t)s * F4 + c];
    float* ap = agg + (size_t)d * F + c * 4;
    atomic_add_f32(ap + 0, v.x);
    atomic_add_f32(ap + 1, v.y);
    atomic_add_f32(ap + 2, v.z);
    atomic_add_f32(ap + 3, v.w);
}

// ---------------------------------------------------------------------------
// Fused SAGE linear: out[n][o] = act( sum_f agg[n][f]*Wl[o][f] + bl[o]
//                                   + sum_f h[n][f]*Wr[o][f] )
// Block = 256 threads = 4 waves; 16 nodes per block (4 nodes per wave).
// Weights staged in LDS as [f4][o] float4 chunks -> conflict-free b128 reads.
// Rows staged in LDS, read as wave-uniform broadcasts.
// ---------------------------------------------------------------------------
__global__ __launch_bounds__(256) void linear_kernel(
    const float* __restrict__ agg, const float* __restrict__ h,
    const float* __restrict__ Wl, const float* __restrict__ bl,
    const float* __restrict__ Wr, float* __restrict__ out,
    int n, int apply_tanh) {
    // WT4[m][f4*64 + o] = W_m[o][4*f4 .. 4*f4+3]
    __shared__ float4 WT4[2][F4 * F];     // 32 KB
    __shared__ float4 rowsA[16][F4];      // 4 KB
    __shared__ float4 rowsH[16][F4];      // 4 KB

    int t = threadIdx.x;

    // Stage weights (each matrix is 64x64 row-major = 1024 float4)
    const float4* Wl4 = (const float4*)Wl;
    const float4* Wr4 = (const float4*)Wr;
    for (int i = t; i < F4 * F; i += 256) {
        int o = i >> 4;          // row (output) index
        int f4 = i & 15;         // chunk index within row
        WT4[0][f4 * F + o] = Wl4[i];
        WT4[1][f4 * F + o] = Wr4[i];
    }

    // Stage 16 node rows of agg and h (256 float4 each, fully coalesced)
    int node0 = blockIdx.x * 16;
    {
        int nl = t >> 4;         // node local 0..15
        int f4 = t & 15;
        int node = node0 + nl;
        if (node < n) {
            rowsA[nl][f4] = ((const float4*)agg)[(size_t)node * F4 + f4];
            rowsH[nl][f4] = ((const float4*)h)[(size_t)node * F4 + f4];
        }
    }
    __syncthreads();

    int wave = t >> 6;
    int lane = t & 63;           // = output feature o
    float bias = bl[lane];
    float acc[4] = {bias, bias, bias, bias};

#pragma unroll
    for (int f4 = 0; f4 < F4; ++f4) {
        float4 wl = WT4[0][f4 * F + lane];
        float4 wr = WT4[1][f4 * F + lane];
#pragma unroll
        for (int j = 0; j < 4; ++j) {
            int nl = wave * 4 + j;
            float4 a = rowsA[nl][f4];
            float4 hh = rowsH[nl][f4];
            acc[j] += a.x * wl.x + a.y * wl.y + a.z * wl.z + a.w * wl.w
                    + hh.x * wr.x + hh.y * wr.y + hh.z * wr.z + hh.w * wr.w;
        }
    }

#pragma unroll
    for (int j = 0; j < 4; ++j) {
        int node = node0 + wave * 4 + j;
        if (node < n) {
            float v = acc[j];
            if (apply_tanh) v = tanhf(v);
            out[(size_t)node * F + lane] = v;
        }
    }
}

// ---------------------------------------------------------------------------
// Launch: 4 SAGE layers. Workspace layout: agg | hA | hB  (N*F floats each).
// ---------------------------------------------------------------------------
extern "C" void kernel_launch(void* const* d_in, const int* in_sizes, int n_in,
                              void* d_out, int out_size, void* d_ws, size_t ws_size,
                              hipStream_t stream) {
    const float* x      = (const float*)d_in[0];
    const int*   edges  = (const int*)d_in[1];
    const float* Wl_in  = (const float*)d_in[2];
    const float* bl_in  = (const float*)d_in[3];
    const float* Wr_in  = (const float*)d_in[4];
    const float* Wl_med = (const float*)d_in[5];
    const float* bl_med = (const float*)d_in[6];
    const float* Wr_med = (const float*)d_in[7];
    const float* Wl_out = (const float*)d_in[8];
    const float* bl_out = (const float*)d_in[9];
    const float* Wr_out = (const float*)d_in[10];

    const int N = in_sizes[0] / F;
    const int E = in_sizes[1] / 2;
    const int* src = edges;
    const int* dst = edges + E;

    float* agg = (float*)d_ws;
    float* hA  = agg + (size_t)N * F;
    float* hB  = hA + (size_t)N * F;
    float* outp = (float*)d_out;

    const size_t agg_bytes = (size_t)N * F * sizeof(float);
    const int scatter_blocks = (E * 16 + 255) / 256;
    const int linear_blocks = (N + 15) / 16;

    // Layer 1: x -> hA (tanh)
    hipMemsetAsync(agg, 0, agg_bytes, stream);
    scatter_kernel<<<scatter_blocks, 256, 0, stream>>>(x, src, dst, agg, E);
    linear_kernel<<<linear_blocks, 256, 0, stream>>>(agg, x, Wl_in, bl_in, Wr_in, hA, N, 1);

    // Layer 2: hA -> hB (tanh)
    hipMemsetAsync(agg, 0, agg_bytes, stream);
    scatter_kernel<<<scatter_blocks, 256, 0, stream>>>(hA, src, dst, agg, E);
    linear_kernel<<<linear_blocks, 256, 0, stream>>>(agg, hA, Wl_med, bl_med, Wr_med, hB, N, 1);

    // Layer 3: hB -> hA (tanh)
    hipMemsetAsync(agg, 0, agg_bytes, stream);
    scatter_kernel<<<scatter_blocks, 256, 0, stream>>>(hB, src, dst, agg, E);
    linear_kernel<<<linear_blocks, 256, 0, stream>>>(agg, hB, Wl_med, bl_med, Wr_med, hA, N, 1);

    // Layer 4: hA -> out (no tanh)
    hipMemsetAsync(agg, 0, agg_bytes, stream);
    scatter_kernel<<<scatter_blocks, 256, 0, stream>>>(hA, src, dst, agg, E);
    linear_kernel<<<linear_blocks, 256, 0, stream>>>(agg, hA, Wl_out, bl_out, Wr_out, outp, N, 0);
}

// Round 2
// 1483.762 us; speedup vs baseline: 3.2640x; 3.2640x over previous
//
#include <hip/hip_runtime.h>
#include <cstdint>

#define F 64          // feature dim (in/hid/out all 64)
#define F4 (F/4)      // float4 chunks per row
#define SCAN_BLK 1024

// ---------------------------------------------------------------------------
// CSR build (per launch; d_ws is re-poisoned every call so no caching).
// ---------------------------------------------------------------------------
__global__ __launch_bounds__(256) void count_kernel(
    const int* __restrict__ dst, int* __restrict__ deg, int E) {
    int e = blockIdx.x * 256 + threadIdx.x;
    if (e < E) atomicAdd(&deg[dst[e]], 1);
}

// Per-block exclusive scan; block totals to blockSums.
__global__ __launch_bounds__(SCAN_BLK) void scan_blocks_kernel(
    const int* __restrict__ deg, int* __restrict__ ex,
    int* __restrict__ blockSums, int n) {
    __shared__ int sh[SCAN_BLK];
    int t = threadIdx.x;
    int i = blockIdx.x * SCAN_BLK + t;
    int v = (i < n) ? deg[i] : 0;
    sh[t] = v;
    __syncthreads();
    for (int off = 1; off < SCAN_BLK; off <<= 1) {
        int add = (t >= off) ? sh[t - off] : 0;
        __syncthreads();
        sh[t] += add;
        __syncthreads();
    }
    int incl = sh[t];
    if (i < n) ex[i] = incl - v;  // exclusive within block
    if (t == SCAN_BLK - 1) blockSums[blockIdx.x] = incl;
}

// Single-block exclusive scan of blockSums (nb <= 1024).
__global__ __launch_bounds__(SCAN_BLK) void scan_sums_kernel(
    int* __restrict__ blockSums, int nb) {
    __shared__ int sh[SCAN_BLK];
    int t = threadIdx.x;
    int v = (t < nb) ? blockSums[t] : 0;
    sh[t] = v;
    __syncthreads();
    for (int off = 1; off < SCAN_BLK; off <<= 1) {
        int add = (t >= off) ? sh[t - off] : 0;
        __syncthreads();
        sh[t] += add;
        __syncthreads();
    }
    if (t < nb) blockSums[t] = sh[t] - v;  // exclusive
}

__global__ __launch_bounds__(256) void add_offsets_kernel(
    int* __restrict__ ex, const int* __restrict__ blockSums,
    int* __restrict__ cursor, int n, int E) {
    int i = blockIdx.x * 256 + threadIdx.x;
    if (i < n) {
        int v = ex[i] + blockSums[i >> 10];
        ex[i] = v;
        cursor[i] = v;
    }
    if (i == 0) ex[n] = E;
}

__global__ __launch_bounds__(256) void fill_kernel(
    const int* __restrict__ src, const int* __restrict__ dst,
    int* __restrict__ cursor, int* __restrict__ csrSrc, int E) {
    int e = blockIdx.x * 256 + threadIdx.x;
    if (e < E) {
        int p = atomicAdd(&cursor[dst[e]], 1);
        csrSrc[p] = src[e];
    }
}

// ---------------------------------------------------------------------------
// Fused SAGE layer: per node i,
//   agg = sum_{j in N(i)} h[j]            (CSR gather, no atomics)
//   out = act( agg @ Wl^T + bl + h[i] @ Wr^T )
// Block = 256 threads: gather phase uses 16 threads/node (one float4 chunk
// each, coalesced 256B row reads); matvec phase uses 1 lane/output, 4 nodes
// per wave, weights staged transposed in LDS (conflict-free b128).
// ---------------------------------------------------------------------------
__global__ __launch_bounds__(256) void sage_layer(
    const float* __restrict__ h, const int* __restrict__ rowStart,
    const int* __restrict__ csrSrc,
    const float* __restrict__ Wl, const float* __restrict__ bl,
    const float* __restrict__ Wr, float* __restrict__ out,
    int n, int apply_tanh) {
    __shared__ float4 WT4[2][F4 * F];   // 32 KB
    __shared__ float4 rowsA[16][F4];    // 4 KB
    __shared__ float4 rowsH[16][F4];    // 4 KB

    int t = threadIdx.x;

    // Stage weights transposed: WT4[m][f4*64 + o] = W_m[o][4f4..4f4+3]
    const float4* Wl4 = (const float4*)Wl;
    const float4* Wr4 = (const float4*)Wr;
#pragma unroll
    for (int i = t; i < F4 * F; i += 256) {
        int o = i >> 4;
        int f4 = i & 15;
        WT4[0][f4 * F + o] = Wl4[i];
        WT4[1][f4 * F + o] = Wr4[i];
    }

    // Gather phase: 16 threads per node, ILP-2 over the edge list.
    const float4* h4 = (const float4*)h;
    int node0 = blockIdx.x * 16;
    int nl = t >> 4;
    int c = t & 15;
    int node = node0 + nl;
    float4 acc = make_float4(0.f, 0.f, 0.f, 0.f);
    float4 self = make_float4(0.f, 0.f, 0.f, 0.f);
    if (node < n) {
        self = h4[(size_t)node * F4 + c];
        int beg = rowStart[node];
        int end = rowStart[node + 1];
        int e = beg;
        for (; e + 1 < end; e += 2) {
            int s0 = csrSrc[e];
            int s1 = csrSrc[e + 1];
            float4 v0 = h4[(size_t)s0 * F4 + c];
            float4 v1 = h4[(size_t)s1 * F4 + c];
            acc.x += v0.x + v1.x;
            acc.y += v0.y + v1.y;
            acc.z += v0.z + v1.z;
            acc.w += v0.w + v1.w;
        }
        if (e < end) {
            float4 v0 = h4[(size_t)csrSrc[e] * F4 + c];
            acc.x += v0.x; acc.y += v0.y; acc.z += v0.z; acc.w += v0.w;
        }
    }
    rowsA[nl][c] = acc;
    rowsH[nl][c] = self;
    __syncthreads();

    // Matvec phase: lane = output feature, 4 nodes per wave.
    int wave = t >> 6;
    int lane = t & 63;
    float bias = bl[lane];
    float r[4] = {bias, bias, bias, bias};

#pragma unroll
    for (int f4 = 0; f4 < F4; ++f4) {
        float4 wl = WT4[0][f4 * F + lane];
        float4 wr = WT4[1][f4 * F + lane];
#pragma unroll
        for (int j = 0; j < 4; ++j) {
            int nj = wave * 4 + j;
            float4 a = rowsA[nj][f4];
            float4 hh = rowsH[nj][f4];
            r[j] += a.x * wl.x + a.y * wl.y + a.z * wl.z + a.w * wl.w
                  + hh.x * wr.x + hh.y * wr.y + hh.z * wr.z + hh.w * wr.w;
        }
    }

#pragma unroll
    for (int j = 0; j < 4; ++j) {
        int nj = node0 + wave * 4 + j;
        if (nj < n) {
            float v = r[j];
            if (apply_tanh) v = tanhf(v);
            out[(size_t)nj * F + lane] = v;
        }
    }
}

// ---------------------------------------------------------------------------
// Launch
// ---------------------------------------------------------------------------
extern "C" void kernel_launch(void* const* d_in, const int* in_sizes, int n_in,
                              void* d_out, int out_size, void* d_ws, size_t ws_size,
                              hipStream_t stream) {
    const float* x      = (const float*)d_in[0];
    const int*   edges  = (const int*)d_in[1];
    const float* Wl_in  = (const float*)d_in[2];
    const float* bl_in  = (const float*)d_in[3];
    const float* Wr_in  = (const float*)d_in[4];
    const float* Wl_med = (const float*)d_in[5];
    const float* bl_med = (const float*)d_in[6];
    const float* Wr_med = (const float*)d_in[7];
    const float* Wl_out = (const float*)d_in[8];
    const float* bl_out = (const float*)d_in[9];
    const float* Wr_out = (const float*)d_in[10];

    const int N = in_sizes[0] / F;
    const int E = in_sizes[1] / 2;
    const int* src = edges;
    const int* dst = edges + E;

    // Workspace layout
    float* hA = (float*)d_ws;                   // N*F
    float* hB = hA + (size_t)N * F;             // N*F
    int* rowStart  = (int*)(hB + (size_t)N * F);// N+1
    int* deg       = rowStart + (N + 1);        // N
    int* cursor    = deg + N;                   // N
    int* blockSums = cursor + N;                // <=1024
    int* csrSrc    = blockSums + SCAN_BLK;      // E
    float* outp = (float*)d_out;

    const int nb_scan = (N + SCAN_BLK - 1) / SCAN_BLK;
    const int eb = (E + 255) / 256;
    const int layer_blocks = (N + 15) / 16;

    // --- CSR build ---
    hipMemsetAsync(deg, 0, (size_t)N * sizeof(int), stream);
    count_kernel<<<eb, 256, 0, stream>>>(dst, deg, E);
    scan_blocks_kernel<<<nb_scan, SCAN_BLK, 0, stream>>>(deg, rowStart, blockSums, N);
    scan_sums_kernel<<<1, SCAN_BLK, 0, stream>>>(blockSums, nb_scan);
    add_offsets_kernel<<<(N + 255) / 256, 256, 0, stream>>>(rowStart, blockSums, cursor, N, E);
    fill_kernel<<<eb, 256, 0, stream>>>(src, dst, cursor, csrSrc, E);

    // --- 4 fused SAGE layers ---
    sage_layer<<<layer_blocks, 256, 0, stream>>>(x,  rowStart, csrSrc, Wl_in,  bl_in,  Wr_in,  hA,   N, 1);
    sage_layer<<<layer_blocks, 256, 0, stream>>>(hA, rowStart, csrSrc, Wl_med, bl_med, Wr_med, hB,   N, 1);
    sage_layer<<<layer_blocks, 256, 0, stream>>>(hB, rowStart, csrSrc, Wl_med, bl_med, Wr_med, hA,   N, 1);
    sage_layer<<<layer_blocks, 256, 0, stream>>>(hA, rowStart, csrSrc, Wl_out, bl_out, Wr_out, outp, N, 0);
}

// Round 3
// 733.870 us; speedup vs baseline: 6.5993x; 2.0218x over previous
//
#include <hip/hip_runtime.h>
#include <cstdint>

#define F 64
#define F4C 16         // float4 chunks per 64-float row
#define NPB 64         // nodes per sage block
#define SCAN_BLK 1024

// ---------------------------------------------------------------------------
// CSR build
// ---------------------------------------------------------------------------
__global__ __launch_bounds__(256) void count_kernel(
    const int* __restrict__ dst, int* __restrict__ deg, int E) {
    int e = blockIdx.x * 256 + threadIdx.x;
    if (e < E) atomicAdd(&deg[dst[e]], 1);
}

__global__ __launch_bounds__(SCAN_BLK) void scan_blocks_kernel(
    const int* __restrict__ deg, int* __restrict__ ex,
    int* __restrict__ blockSums, int n) {
    __shared__ int sh[SCAN_BLK];
    int t = threadIdx.x;
    int i = blockIdx.x * SCAN_BLK + t;
    int v = (i < n) ? deg[i] : 0;
    sh[t] = v;
    __syncthreads();
    for (int off = 1; off < SCAN_BLK; off <<= 1) {
        int add = (t >= off) ? sh[t - off] : 0;
        __syncthreads();
        sh[t] += add;
        __syncthreads();
    }
    int incl = sh[t];
    if (i < n) ex[i] = incl - v;
    if (t == SCAN_BLK - 1) blockSums[blockIdx.x] = incl;
}

__global__ __launch_bounds__(SCAN_BLK) void scan_sums_kernel(
    int* __restrict__ blockSums, int nb) {
    __shared__ int sh[SCAN_BLK];
    int t = threadIdx.x;
    int v = (t < nb) ? blockSums[t] : 0;
    sh[t] = v;
    __syncthreads();
    for (int off = 1; off < SCAN_BLK; off <<= 1) {
        int add = (t >= off) ? sh[t - off] : 0;
        __syncthreads();
        sh[t] += add;
        __syncthreads();
    }
    if (t < nb) blockSums[t] = sh[t] - v;
}

__global__ __launch_bounds__(256) void add_offsets_kernel(
    int* __restrict__ ex, const int* __restrict__ blockSums,
    int* __restrict__ cursor, int n, int E) {
    int i = blockIdx.x * 256 + threadIdx.x;
    if (i < n) {
        int v = ex[i] + blockSums[i >> 10];
        ex[i] = v;
        cursor[i] = v;
    }
    if (i == 0) ex[n] = E;
}

__global__ __launch_bounds__(256) void fill_kernel(
    const int* __restrict__ src, const int* __restrict__ dst,
    int* __restrict__ cursor, int* __restrict__ csrSrc, int E) {
    int e = blockIdx.x * 256 + threadIdx.x;
    if (e < E) {
        int p = atomicAdd(&cursor[dst[e]], 1);
        csrSrc[p] = src[e];
    }
}

// ---------------------------------------------------------------------------
// Weight pre-swizzle: for each of 3 layer-sets, build a 2048-float4 image
//   WSw[set][m*1024 + f4*64 + k*16 + oc] = W_m[4*oc + k][4*f4 .. 4*f4+3]
// so sage blocks stage LDS with a linear conflict-free copy, and matvec
// reads (k*16 + oc) land 2 addrs/bank (free).
// ---------------------------------------------------------------------------
__global__ __launch_bounds__(256) void prep_weights(
    const float* __restrict__ Wl0, const float* __restrict__ Wr0,
    const float* __restrict__ Wl1, const float* __restrict__ Wr1,
    const float* __restrict__ Wl2, const float* __restrict__ Wr2,
    float4* __restrict__ WSw) {
    int g = blockIdx.x * 256 + threadIdx.x;
    if (g >= 3 * 2048) return;
    int set = g >> 11;
    int r = g & 2047;
    int m = r >> 10;
    int q = r & 1023;
    int f4 = q >> 6;
    int kk = (q >> 4) & 3;
    int oc = q & 15;
    const float* W = (set == 0) ? (m ? Wr0 : Wl0)
                   : (set == 1) ? (m ? Wr1 : Wl1)
                                : (m ? Wr2 : Wl2);
    const float4* W4 = (const float4*)W;
    WSw[g] = W4[(4 * oc + kk) * F4C + f4];
}

// rows LDS slot (float4 units): 32 chunks per node (16 agg + 16 self),
// low-4 chunk bits XOR-swizzled by ((n>>2)&3)<<2 so phase-2's 4-address
// reads (stride 4 nodes) spread over 2 banks ≈ conflict-free.
__device__ __forceinline__ int row_slot(int n, int c) {
    return n * 32 + (c & 16) + ((c & 15) ^ (((n >> 2) & 3) << 2));
}

// ---------------------------------------------------------------------------
// Fused SAGE layer, 64 nodes/block.
// Phase 1: CSR gather (16 threads/node, float4 chunk each, unroll-4 ILP)
//          + self row -> swizzled LDS rows.
// Phase 2: register-tile matvec: lane = (ng = lane>>4) x (oc = lane&15),
//          4 nodes x 4 outputs per lane; 8 LDS b128 : 64 FMA per step.
// ---------------------------------------------------------------------------
__global__ __launch_bounds__(256, 2) void sage_layer(
    const float* __restrict__ h, const int* __restrict__ rowStart,
    const int* __restrict__ csrSrc, const float4* __restrict__ WSwSet,
    const float* __restrict__ bl, float* __restrict__ out,
    int n, int apply_tanh) {
    __shared__ float4 WT[2048];        // 32 KB swizzled [Wl;Wr]
    __shared__ float4 rows[NPB * 32];  // 32 KB

    int t = threadIdx.x;

    // Stage weights: linear coalesced copy, conflict-free LDS writes.
#pragma unroll
    for (int i = 0; i < 8; ++i) WT[t + 256 * i] = WSwSet[t + 256 * i];

    // ---- Phase 1: gather + self ----
    const float4* h4 = (const float4*)h;
    int node0 = blockIdx.x * NPB;
    int nl = t >> 4, c = t & 15;
#pragma unroll
    for (int p = 0; p < 4; ++p) {
        int local = p * 16 + nl;
        int node = node0 + local;
        float4 acc = make_float4(0.f, 0.f, 0.f, 0.f);
        float4 self = make_float4(0.f, 0.f, 0.f, 0.f);
        if (node < n) {
            self = h4[(size_t)node * F4C + c];
            int e = rowStart[node];
            int end = rowStart[node + 1];
            for (; e + 3 < end; e += 4) {
                int s0 = csrSrc[e + 0];
                int s1 = csrSrc[e + 1];
                int s2 = csrSrc[e + 2];
                int s3 = csrSrc[e + 3];
                float4 v0 = h4[(size_t)s0 * F4C + c];
                float4 v1 = h4[(size_t)s1 * F4C + c];
                float4 v2 = h4[(size_t)s2 * F4C + c];
                float4 v3 = h4[(size_t)s3 * F4C + c];
                acc.x += (v0.x + v1.x) + (v2.x + v3.x);
                acc.y += (v0.y + v1.y) + (v2.y + v3.y);
                acc.z += (v0.z + v1.z) + (v2.z + v3.z);
                acc.w += (v0.w + v1.w) + (v2.w + v3.w);
            }
            for (; e < end; ++e) {
                float4 v0 = h4[(size_t)csrSrc[e] * F4C + c];
                acc.x += v0.x; acc.y += v0.y; acc.z += v0.z; acc.w += v0.w;
            }
        }
        rows[row_slot(local, c)] = acc;
        rows[row_slot(local, 16 + c)] = self;
    }
    __syncthreads();

    // ---- Phase 2: matvec ----
    int w = t >> 6;
    int lane = t & 63;
    int ng = lane >> 4;
    int oc = lane & 15;
    int nbase = w * 16 + ng * 4;

    float4 b4 = ((const float4*)bl)[oc];
    float4 accv[4];
#pragma unroll
    for (int j = 0; j < 4; ++j) accv[j] = b4;

#pragma unroll
    for (int m = 0; m < 2; ++m) {
        const float4* wb = WT + m * 1024;
#pragma unroll 4
        for (int f4 = 0; f4 < 16; ++f4) {
            float4 w0 = wb[f4 * 64 + oc];
            float4 w1 = wb[f4 * 64 + 16 + oc];
            float4 w2 = wb[f4 * 64 + 32 + oc];
            float4 w3 = wb[f4 * 64 + 48 + oc];
            int cidx = m * 16 + f4;
#pragma unroll
            for (int j = 0; j < 4; ++j) {
                float4 a = rows[row_slot(nbase + j, cidx)];
                accv[j].x += a.x * w0.x + a.y * w0.y + a.z * w0.z + a.w * w0.w;
                accv[j].y += a.x * w1.x + a.y * w1.y + a.z * w1.z + a.w * w1.w;
                accv[j].z += a.x * w2.x + a.y * w2.y + a.z * w2.z + a.w * w2.w;
                accv[j].w += a.x * w3.x + a.y * w3.y + a.z * w3.z + a.w * w3.w;
            }
        }
    }

    float4* out4 = (float4*)out;
#pragma unroll
    for (int j = 0; j < 4; ++j) {
        int node = node0 + nbase + j;
        if (node < n) {
            float4 v = accv[j];
            if (apply_tanh) {
                v.x = tanhf(v.x); v.y = tanhf(v.y);
                v.z = tanhf(v.z); v.w = tanhf(v.w);
            }
            out4[(size_t)node * F4C + oc] = v;
        }
    }
}

// ---------------------------------------------------------------------------
// Launch
// ---------------------------------------------------------------------------
extern "C" void kernel_launch(void* const* d_in, const int* in_sizes, int n_in,
                              void* d_out, int out_size, void* d_ws, size_t ws_size,
                              hipStream_t stream) {
    const float* x      = (const float*)d_in[0];
    const int*   edges  = (const int*)d_in[1];
    const float* Wl_in  = (const float*)d_in[2];
    const float* bl_in  = (const float*)d_in[3];
    const float* Wr_in  = (const float*)d_in[4];
    const float* Wl_med = (const float*)d_in[5];
    const float* bl_med = (const float*)d_in[6];
    const float* Wr_med = (const float*)d_in[7];
    const float* Wl_out = (const float*)d_in[8];
    const float* bl_out = (const float*)d_in[9];
    const float* Wr_out = (const float*)d_in[10];

    const int N = in_sizes[0] / F;
    const int E = in_sizes[1] / 2;
    const int* src = edges;
    const int* dst = edges + E;

    // Workspace layout (WSw first for float4 alignment)
    float4* WSw = (float4*)d_ws;                     // 6144 float4
    float* hA = (float*)(WSw + 6144);                // N*F
    float* hB = hA + (size_t)N * F;                  // N*F
    int* rowStart  = (int*)(hB + (size_t)N * F);     // N+1
    int* deg       = rowStart + (N + 1);             // N
    int* cursor    = deg + N;                        // N
    int* blockSums = cursor + N;                     // SCAN_BLK
    int* csrSrc    = blockSums + SCAN_BLK;           // E
    float* outp = (float*)d_out;

    const int nb_scan = (N + SCAN_BLK - 1) / SCAN_BLK;
    const int eb = (E + 255) / 256;
    const int layer_blocks = (N + NPB - 1) / NPB;

    // CSR build
    hipMemsetAsync(deg, 0, (size_t)N * sizeof(int), stream);
    count_kernel<<<eb, 256, 0, stream>>>(dst, deg, E);
    scan_blocks_kernel<<<nb_scan, SCAN_BLK, 0, stream>>>(deg, rowStart, blockSums, N);
    scan_sums_kernel<<<1, SCAN_BLK, 0, stream>>>(blockSums, nb_scan);
    add_offsets_kernel<<<(N + 255) / 256, 256, 0, stream>>>(rowStart, blockSums, cursor, N, E);
    fill_kernel<<<eb, 256, 0, stream>>>(src, dst, cursor, csrSrc, E);

    // Weight pre-swizzle (sets: 0=in, 1=med, 2=out)
    prep_weights<<<24, 256, 0, stream>>>(Wl_in, Wr_in, Wl_med, Wr_med,
                                         Wl_out, Wr_out, WSw);

    // 4 fused SAGE layers
    sage_layer<<<layer_blocks, 256, 0, stream>>>(x,  rowStart, csrSrc, WSw + 0,    bl_in,  hA,   N, 1);
    sage_layer<<<layer_blocks, 256, 0, stream>>>(hA, rowStart, csrSrc, WSw + 2048, bl_med, hB,   N, 1);
    sage_layer<<<layer_blocks, 256, 0, stream>>>(hB, rowStart, csrSrc, WSw + 2048, bl_med, hA,   N, 1);
    sage_layer<<<layer_blocks, 256, 0, stream>>>(hA, rowStart, csrSrc, WSw + 4096, bl_out, outp, N, 0);
}

// Round 4
// 572.308 us; speedup vs baseline: 8.4623x; 1.2823x over previous
//
#include <hip/hip_runtime.h>
#include <cstdint>

#define F 64
#define NPB 128        // nodes per matvec block
#define SCAN_BLK 1024

// ---------------------------------------------------------------------------
// helpers: bf16 <-> fp32
// ---------------------------------------------------------------------------
__device__ __forceinline__ unsigned short f2b(float f) {     // RNE round
    unsigned u = __float_as_uint(f);
    unsigned r = u + 0x7fffu + ((u >> 16) & 1u);
    return (unsigned short)(r >> 16);
}
__device__ __forceinline__ float4 b2f4(uint2 u) {
    return make_float4(__uint_as_float(u.x << 16),
                       __uint_as_float(u.x & 0xffff0000u),
                       __uint_as_float(u.y << 16),
                       __uint_as_float(u.y & 0xffff0000u));
}

// ---------------------------------------------------------------------------
// CSR build
// ---------------------------------------------------------------------------
__global__ __launch_bounds__(256) void count_kernel(
    const int* __restrict__ dst, int* __restrict__ deg, int E) {
    int e = blockIdx.x * 256 + threadIdx.x;
    if (e < E) atomicAdd(&deg[dst[e]], 1);
}

__global__ __launch_bounds__(SCAN_BLK) void scan_blocks_kernel(
    const int* __restrict__ deg, int* __restrict__ ex,
    int* __restrict__ blockSums, int n) {
    __shared__ int sh[SCAN_BLK];
    int t = threadIdx.x;
    int i = blockIdx.x * SCAN_BLK + t;
    int v = (i < n) ? deg[i] : 0;
    sh[t] = v;
    __syncthreads();
    for (int off = 1; off < SCAN_BLK; off <<= 1) {
        int add = (t >= off) ? sh[t - off] : 0;
        __syncthreads();
        sh[t] += add;
        __syncthreads();
    }
    int incl = sh[t];
    if (i < n) ex[i] = incl - v;
    if (t == SCAN_BLK - 1) blockSums[blockIdx.x] = incl;
}

__global__ __launch_bounds__(SCAN_BLK) void scan_sums_kernel(
    int* __restrict__ blockSums, int nb) {
    __shared__ int sh[SCAN_BLK];
    int t = threadIdx.x;
    int v = (t < nb) ? blockSums[t] : 0;
    sh[t] = v;
    __syncthreads();
    for (int off = 1; off < SCAN_BLK; off <<= 1) {
        int add = (t >= off) ? sh[t - off] : 0;
        __syncthreads();
        sh[t] += add;
        __syncthreads();
    }
    if (t < nb) blockSums[t] = sh[t] - v;
}

__global__ __launch_bounds__(256) void add_offsets_kernel(
    int* __restrict__ ex, const int* __restrict__ blockSums,
    int* __restrict__ cursor, int n, int E) {
    int i = blockIdx.x * 256 + threadIdx.x;
    if (i < n) {
        int v = ex[i] + blockSums[i >> 10];
        ex[i] = v;
        cursor[i] = v;
    }
    if (i == 0) ex[n] = E;
}

__global__ __launch_bounds__(256) void fill_kernel(
    const int* __restrict__ src, const int* __restrict__ dst,
    int* __restrict__ cursor, int* __restrict__ csrSrc, int E) {
    int e = blockIdx.x * 256 + threadIdx.x;
    if (e < E) {
        int p = atomicAdd(&cursor[dst[e]], 1);
        csrSrc[p] = src[e];
    }
}

// ---------------------------------------------------------------------------
// Prep: weight swizzle (blocks 0..23) + x -> bf16 (remaining blocks).
//   WSw[set][m*1024 + f4*64 + k*16 + oc] = W_m[4*oc + k][4*f4 .. 4*f4+3]
// ---------------------------------------------------------------------------
__global__ __launch_bounds__(256) void prep_kernel(
    const float* __restrict__ Wl0, const float* __restrict__ Wr0,
    const float* __restrict__ Wl1, const float* __restrict__ Wr1,
    const float* __restrict__ Wl2, const float* __restrict__ Wr2,
    float4* __restrict__ WSw,
    const float* __restrict__ x, ushort* __restrict__ xb, int nElem) {
    int b = blockIdx.x;
    int t = threadIdx.x;
    if (b < 24) {
        int g = b * 256 + t;
        if (g >= 3 * 2048) return;
        int set = g >> 11;
        int r = g & 2047;
        int m = r >> 10;
        int q = r & 1023;
        int f4 = q >> 6;
        int kk = (q >> 4) & 3;
        int oc = q & 15;
        const float* W = (set == 0) ? (m ? Wr0 : Wl0)
                       : (set == 1) ? (m ? Wr1 : Wl1)
                                    : (m ? Wr2 : Wl2);
        const float4* W4 = (const float4*)W;
        WSw[g] = W4[(4 * oc + kk) * (F / 4) + f4];
    } else {
        int i = (b - 24) * 256 + t;           // float4 index
        int n4 = nElem >> 2;
        if (i < n4) {
            float4 v = ((const float4*)x)[i];
            uint2 o;
            o.x = (unsigned)f2b(v.x) | ((unsigned)f2b(v.y) << 16);
            o.y = (unsigned)f2b(v.z) | ((unsigned)f2b(v.w) << 16);
            ((uint2*)xb)[i] = o;
        }
    }
}

// ---------------------------------------------------------------------------
// Gather: agg[node] = sum_{j in N(node)} hb[j]   (bf16 in, fp32 out)
// 8 lanes per node, each lane owns 8 columns (one uint4 = 8 bf16 = 16 B).
// No LDS; high occupancy for latency hiding.
// ---------------------------------------------------------------------------
__device__ __forceinline__ void add8(float* a, uint4 u) {
    const unsigned* p = (const unsigned*)&u;
#pragma unroll
    for (int i = 0; i < 4; ++i) {
        a[2 * i + 0] += __uint_as_float(p[i] << 16);
        a[2 * i + 1] += __uint_as_float(p[i] & 0xffff0000u);
    }
}

__global__ __launch_bounds__(256, 6) void gather_kernel(
    const ushort* __restrict__ hb, const int* __restrict__ rowStart,
    const int* __restrict__ csrSrc, float* __restrict__ agg, int n) {
    int gid = blockIdx.x * 256 + threadIdx.x;
    int node = gid >> 3;
    int c = gid & 7;
    if (node >= n) return;

    const uint4* h16 = (const uint4*)hb;     // row = 8 uint4
    float a[8] = {0.f, 0.f, 0.f, 0.f, 0.f, 0.f, 0.f, 0.f};

    int e = rowStart[node];
    int end = rowStart[node + 1];
    for (; e + 1 < end; e += 2) {
        int s0 = csrSrc[e];
        int s1 = csrSrc[e + 1];
        uint4 u0 = h16[(size_t)s0 * 8 + c];
        uint4 u1 = h16[(size_t)s1 * 8 + c];
        add8(a, u0);
        add8(a, u1);
    }
    if (e < end) {
        uint4 u0 = h16[(size_t)csrSrc[e] * 8 + c];
        add8(a, u0);
    }

    float4* o = (float4*)(agg + (size_t)node * F);
    o[2 * c + 0] = make_float4(a[0], a[1], a[2], a[3]);
    o[2 * c + 1] = make_float4(a[4], a[5], a[6], a[7]);
}

// ---------------------------------------------------------------------------
// Matvec: out[n] = act( agg[n] @ Wl^T + bl + hb[n] @ Wr^T )
// NPB=128 nodes/block, 256 threads. LDS: weights 32 KB + agg fp32 32 KB.
// Thread tile: 8 nodes x 4 outputs. Self rows read from global bf16 (L1-hot).
// flags: bit0 = tanh, bit1 = bf16 output.
// ---------------------------------------------------------------------------
__global__ __launch_bounds__(256, 2) void matvec_kernel(
    const float* __restrict__ agg, const ushort* __restrict__ hb,
    const float4* __restrict__ WSwSet, const float* __restrict__ bl,
    void* __restrict__ out, int n, int flags) {
    __shared__ float4 WT[2048];      // 32 KB swizzled [Wl;Wr]
    __shared__ float4 aggT[NPB * 16];// 32 KB, slot = nn*16 + (f4 ^ ((nn>>3)&15))

    int t = threadIdx.x;
    int node0 = blockIdx.x * NPB;

    // Stage weights (linear, conflict-free)
#pragma unroll
    for (int i = 0; i < 8; ++i) WT[t + 256 * i] = WSwSet[t + 256 * i];

    // Stage agg tile (coalesced global float4 reads; unguarded — epilogue guards)
    const float4* aggG = (const float4*)agg + (size_t)node0 * 16;
#pragma unroll
    for (int k = 0; k < 8; ++k) {
        int idx = k * 256 + t;
        int nn = idx >> 4;
        int f4 = idx & 15;
        aggT[nn * 16 + (f4 ^ ((nn >> 3) & 15))] = aggG[idx];
    }
    __syncthreads();

    int w = t >> 6;
    int lane = t & 63;
    int ng = lane >> 4;
    int oc = lane & 15;
    int nbase = w * 32 + ng * 8;
    int sw = (nbase >> 3) & 15;      // constant across j (nbase 8-aligned)

    float4 b4 = ((const float4*)bl)[oc];
    float4 acc[8];
#pragma unroll
    for (int j = 0; j < 8; ++j) acc[j] = b4;

    // m = 0: agg @ Wl
#pragma unroll 4
    for (int f4 = 0; f4 < 16; ++f4) {
        float4 w0 = WT[f4 * 64 + oc];
        float4 w1 = WT[f4 * 64 + 16 + oc];
        float4 w2 = WT[f4 * 64 + 32 + oc];
        float4 w3 = WT[f4 * 64 + 48 + oc];
        int slot = f4 ^ sw;
#pragma unroll
        for (int j = 0; j < 8; ++j) {
            float4 a = aggT[(nbase + j) * 16 + slot];
            acc[j].x += a.x * w0.x + a.y * w0.y + a.z * w0.z + a.w * w0.w;
            acc[j].y += a.x * w1.x + a.y * w1.y + a.z * w1.z + a.w * w1.w;
            acc[j].z += a.x * w2.x + a.y * w2.y + a.z * w2.z + a.w * w2.w;
            acc[j].w += a.x * w3.x + a.y * w3.y + a.z * w3.z + a.w * w3.w;
        }
    }

    // m = 1: self @ Wr, rows from global bf16 (block tile is L1-resident)
    const uint2* hb2 = (const uint2*)hb + (size_t)node0 * 16;
#pragma unroll 4
    for (int f4 = 0; f4 < 16; ++f4) {
        float4 w0 = WT[1024 + f4 * 64 + oc];
        float4 w1 = WT[1024 + f4 * 64 + 16 + oc];
        float4 w2 = WT[1024 + f4 * 64 + 32 + oc];
        float4 w3 = WT[1024 + f4 * 64 + 48 + oc];
#pragma unroll
        for (int j = 0; j < 8; ++j) {
            float4 a = b2f4(hb2[(nbase + j) * 16 + f4]);
            acc[j].x += a.x * w0.x + a.y * w0.y + a.z * w0.z + a.w * w0.w;
            acc[j].y += a.x * w1.x + a.y * w1.y + a.z * w1.z + a.w * w1.w;
            acc[j].z += a.x * w2.x + a.y * w2.y + a.z * w2.z + a.w * w2.w;
            acc[j].w += a.x * w3.x + a.y * w3.y + a.z * w3.z + a.w * w3.w;
        }
    }

    // Epilogue
#pragma unroll
    for (int j = 0; j < 8; ++j) {
        int node = node0 + nbase + j;
        if (node < n) {
            float4 v = acc[j];
            if (flags & 1) {
                v.x = tanhf(v.x); v.y = tanhf(v.y);
                v.z = tanhf(v.z); v.w = tanhf(v.w);
            }
            if (flags & 2) {
                uint2 o;
                o.x = (unsigned)f2b(v.x) | ((unsigned)f2b(v.y) << 16);
                o.y = (unsigned)f2b(v.z) | ((unsigned)f2b(v.w) << 16);
                ((uint2*)out)[(size_t)node * 16 + oc] = o;
            } else {
                ((float4*)out)[(size_t)node * 16 + oc] = v;
            }
        }
    }
}

// ---------------------------------------------------------------------------
// Launch
// ---------------------------------------------------------------------------
extern "C" void kernel_launch(void* const* d_in, const int* in_sizes, int n_in,
                              void* d_out, int out_size, void* d_ws, size_t ws_size,
                              hipStream_t stream) {
    const float* x      = (const float*)d_in[0];
    const int*   edges  = (const int*)d_in[1];
    const float* Wl_in  = (const float*)d_in[2];
    const float* bl_in  = (const float*)d_in[3];
    const float* Wr_in  = (const float*)d_in[4];
    const float* Wl_med = (const float*)d_in[5];
    const float* bl_med = (const float*)d_in[6];
    const float* Wr_med = (const float*)d_in[7];
    const float* Wl_out = (const float*)d_in[8];
    const float* bl_out = (const float*)d_in[9];
    const float* Wr_out = (const float*)d_in[10];

    const int N = in_sizes[0] / F;
    const int E = in_sizes[1] / 2;
    const int* src = edges;
    const int* dst = edges + E;

    // Workspace layout (16B-aligned chunks)
    float4* WSw = (float4*)d_ws;                       // 6144 float4
    float*  agg = (float*)(WSw + 6144);                // N*F fp32
    ushort* xb  = (ushort*)(agg + (size_t)N * F);      // N*F bf16
    ushort* hAb = xb + (size_t)N * F;                  // N*F bf16
    ushort* hBb = hAb + (size_t)N * F;                 // N*F bf16
    int* rowStart  = (int*)(hBb + (size_t)N * F);      // N+1
    int* deg       = rowStart + (N + 1);               // N
    int* cursor    = deg + N;                          // N
    int* blockSums = cursor + N;                       // SCAN_BLK
    int* csrSrc    = blockSums + SCAN_BLK;             // E

    const int nb_scan = (N + SCAN_BLK - 1) / SCAN_BLK;
    const int eb = (E + 255) / 256;
    const int gather_blocks = (N * 8 + 255) / 256;
    const int mv_blocks = (N + NPB - 1) / NPB;
    const int prep_blocks = 24 + (N * F / 4 + 255) / 256;

    // Prep (weights + x->bf16)
    prep_kernel<<<prep_blocks, 256, 0, stream>>>(Wl_in, Wr_in, Wl_med, Wr_med,
                                                 Wl_out, Wr_out, WSw, x, xb, N * F);

    // CSR build
    hipMemsetAsync(deg, 0, (size_t)N * sizeof(int), stream);
    count_kernel<<<eb, 256, 0, stream>>>(dst, deg, E);
    scan_blocks_kernel<<<nb_scan, SCAN_BLK, 0, stream>>>(deg, rowStart, blockSums, N);
    scan_sums_kernel<<<1, SCAN_BLK, 0, stream>>>(blockSums, nb_scan);
    add_offsets_kernel<<<(N + 255) / 256, 256, 0, stream>>>(rowStart, blockSums, cursor, N, E);
    fill_kernel<<<eb, 256, 0, stream>>>(src, dst, cursor, csrSrc, E);

    // Layer 1: xb -> hAb (tanh, bf16 out)
    gather_kernel<<<gather_blocks, 256, 0, stream>>>(xb, rowStart, csrSrc, agg, N);
    matvec_kernel<<<mv_blocks, 256, 0, stream>>>(agg, xb, WSw + 0, bl_in, hAb, N, 3);
    // Layer 2: hAb -> hBb
    gather_kernel<<<gather_blocks, 256, 0, stream>>>(hAb, rowStart, csrSrc, agg, N);
    matvec_kernel<<<mv_blocks, 256, 0, stream>>>(agg, hAb, WSw + 2048, bl_med, hBb, N, 3);
    // Layer 3: hBb -> hAb
    gather_kernel<<<gather_blocks, 256, 0, stream>>>(hBb, rowStart, csrSrc, agg, N);
    matvec_kernel<<<mv_blocks, 256, 0, stream>>>(agg, hBb, WSw + 2048, bl_med, hAb, N, 3);
    // Layer 4: hAb -> d_out (no tanh, fp32 out)
    gather_kernel<<<gather_blocks, 256, 0, stream>>>(hAb, rowStart, csrSrc, agg, N);
    matvec_kernel<<<mv_blocks, 256, 0, stream>>>(agg, hAb, WSw + 4096, bl_out, d_out, N, 0);
}